// Round 5
// baseline (401.210 us; speedup 1.0000x reference)
//
#include <hip/hip_runtime.h>

// TFF_Angle: angle force-field energy + force scatter.
// Inputs: 0 dist(N,N) f32 | 1 vec(N,N,3) f32 | 2 forces0(N,3) f32 |
//         3 params(A,2) f32 | 4 coord_idx(A,3) i32 | 5 calc_energy i32 | 6 calc_forces i32
// Output: [energy] ++ forces(N*3), fp32.
//
// R5 structure: 2 dispatches, no workspace, no big LDS.
//   1) init_out_kernel: out[0]=0, out[1..]=forces0.
//   2) angle_direct_kernel: 1 angle/thread, 256-thr blocks, direct global
//      atomicAdd of the 9 force components (1.8M atomics over 12288 dwords
//      ~= 146/address, parallel across L2 channels). Rationale: per-block
//      LDS accumulation only collapsed 7038 updates -> ~5500 distinct slots
//      (1.27x) while costing 48KB zero-init + barrier tail + 12288-slot
//      flush scan. Energy: wave shuffle -> LDS[nw] -> 1 atomic/block.

__global__ void init_out_kernel(float* __restrict__ out,
                                const float* __restrict__ forces0,
                                int nf) {
    int j = blockIdx.x * blockDim.x + threadIdx.x;
    if (j == 0) out[0] = 0.0f;
    if (j < nf) out[1 + j] = forces0[j];
}

#define NT 256   // threads per block (4 waves)

__global__ void __launch_bounds__(NT)
angle_direct_kernel(const float*  __restrict__ dist,
                    const float*  __restrict__ vec,
                    const float2* __restrict__ params,
                    const int*    __restrict__ cidx,
                    const int*    __restrict__ ce_p,
                    const int*    __restrict__ cf_p,
                    float* __restrict__ out,   // [0]=energy, [1..nf]=forces
                    int n_atoms, int n_angles) {
    __shared__ float s_ew[NT / 64];
    const int tid = threadIdx.x;
    const int i   = blockIdx.x * NT + tid;

    const int ce = ce_p[0];
    const int cf = cf_p[0];
    float* __restrict__ f = out + 1;

    float e_acc = 0.0f;
    if (i < n_angles) {
        // coalesced index/param loads
        const int a1 = cidx[3 * i + 0];
        const int a2 = cidx[3 * i + 1];
        const int a3 = cidx[3 * i + 2];
        const float2 kt = params[i];

        // 32-bit gather addressing (max idx 4096*4096*3 < 2^26)
        const unsigned row = (unsigned)a2 * (unsigned)n_atoms;
        const unsigned b21 = row + (unsigned)a1;
        const unsigned b23 = row + (unsigned)a3;
        const float* __restrict__ p21 = vec + 3u * b21;
        const float* __restrict__ p23 = vec + 3u * b23;

        // 4 independent gather instructions — latency overlapped
        const float v21x = p21[0], v21y = p21[1], v21z = p21[2];
        const float v23x = p23[0], v23y = p23[1], v23z = p23[2];
        const float d21 = dist[b21];
        const float d23 = dist[b23];

        float c = v21x * v23x + v21y * v23y + v21z * v23z;
        c = fminf(1.0f, fmaxf(-1.0f, c));
        const float th  = acosf(c);
        const float dth = th - kt.y;

        if (ce) e_acc = kt.x * dth * dth;

        if (cf) {
            const float s2 = fmaxf(0.0f, 1.0f - c * c);
            const float s  = sqrtf(s2);
            const float coef = (s > 0.0f) ? (-2.0f * kt.x * dth / fmaxf(s, 1e-12f)) : 0.0f;
            const float i21 = coef / d21;
            const float i23 = coef / d23;

            const float f0x = i21 * (c * v21x - v23x);
            const float f0y = i21 * (c * v21y - v23y);
            const float f0z = i21 * (c * v21z - v23z);
            const float f2x = i23 * (c * v23x - v21x);
            const float f2y = i23 * (c * v23y - v21y);
            const float f2z = i23 * (c * v23z - v21z);

            atomicAdd(&f[a1 * 3 + 0], f0x);
            atomicAdd(&f[a1 * 3 + 1], f0y);
            atomicAdd(&f[a1 * 3 + 2], f0z);
            atomicAdd(&f[a2 * 3 + 0], -(f0x + f2x));
            atomicAdd(&f[a2 * 3 + 1], -(f0y + f2y));
            atomicAdd(&f[a2 * 3 + 2], -(f0z + f2z));
            atomicAdd(&f[a3 * 3 + 0], f2x);
            atomicAdd(&f[a3 * 3 + 1], f2y);
            atomicAdd(&f[a3 * 3 + 2], f2z);
        }
    }

    if (ce) {
        // wave shuffle reduce -> per-wave slot -> single atomic per block
        for (int off = 32; off > 0; off >>= 1)
            e_acc += __shfl_down(e_acc, off, 64);
        if ((tid & 63) == 0) s_ew[tid >> 6] = e_acc;
        __syncthreads();
        if (tid == 0) {
            float e = s_ew[0];
            #pragma unroll
            for (int w = 1; w < NT / 64; ++w) e += s_ew[w];
            atomicAdd(&out[0], e);
        }
    }
}

extern "C" void kernel_launch(void* const* d_in, const int* in_sizes, int n_in,
                              void* d_out, int out_size, void* d_ws, size_t ws_size,
                              hipStream_t stream) {
    const float*  dist    = (const float*)d_in[0];
    const float*  vec     = (const float*)d_in[1];
    const float*  forces0 = (const float*)d_in[2];
    const float2* params  = (const float2*)d_in[3];
    const int*    cidx    = (const int*)d_in[4];
    const int*    ce_p    = (const int*)d_in[5];
    const int*    cf_p    = (const int*)d_in[6];
    float* out = (float*)d_out;

    const int n_atoms  = in_sizes[2] / 3;
    const int n_angles = in_sizes[4] / 3;
    const int nf = n_atoms * 3;

    init_out_kernel<<<(nf + 1 + 255) / 256, 256, 0, stream>>>(out, forces0, nf);

    const int nb = (n_angles + NT - 1) / NT;   // 782 at A=200k
    angle_direct_kernel<<<nb, NT, 0, stream>>>(dist, vec, params, cidx,
                                               ce_p, cf_p, out,
                                               n_atoms, n_angles);
}